// Round 1
// baseline (463.189 us; speedup 1.0000x reference)
//
#include <hip/hip_runtime.h>
#include <cstdint>
#include <cstddef>

// Problem constants (from reference)
#define BATCH 1024
#define S1 25
#define S2 10
#define FDIM 256
#define HDIM 128
#define NCLS 41
#define MAXDEG 128

// Flip to 0 if harness JAX uses the pre-0.4.30 (non-partitionable) threefry scheme.
#define JAX_PARTITIONABLE 1

// ---------------- Threefry-2x32 (matches jax/_src/prng.py lowering) ----------------
__host__ __device__ static inline void tf2x32(uint32_t k0, uint32_t k1,
                                              uint32_t c0, uint32_t c1,
                                              uint32_t& o0, uint32_t& o1) {
  const uint32_t ks2 = k0 ^ k1 ^ 0x1BD11BDAu;
  uint32_t x0 = c0 + k0, x1 = c1 + k1;
#define TFR(r) { x0 += x1; x1 = (x1 << (r)) | (x1 >> (32 - (r))); x1 ^= x0; }
  TFR(13) TFR(15) TFR(26) TFR(6)
  x0 += k1;  x1 += ks2 + 1u;
  TFR(17) TFR(29) TFR(16) TFR(24)
  x0 += ks2; x1 += k0 + 2u;
  TFR(13) TFR(15) TFR(26) TFR(6)
  x0 += k0;  x1 += k1 + 3u;
  TFR(17) TFR(29) TFR(16) TFR(24)
  x0 += k1;  x1 += ks2 + 4u;
  TFR(13) TFR(15) TFR(26) TFR(6)
  x0 += ks2; x1 += k0 + 5u;
#undef TFR
  o0 = x0; o1 = x1;
}

// random_bits (partitionable): bits[j] = o0 ^ o1 of threefry(key, (0, j))
__device__ static inline uint32_t rand_bits_at(uint32_t kb0, uint32_t kb1, uint32_t j) {
  uint32_t o0, o1;
  tf2x32(kb0, kb1, 0u, j, o0, o1);
  return o0 ^ o1;
}

// ---------------- Sampling kernels ----------------
__global__ void hop1_kernel(const int* __restrict__ node_ids,
                            const int* __restrict__ adj,
                            int* __restrict__ hop1,
                            uint32_t kb0, uint32_t kb1) {
  int j = blockIdx.x * blockDim.x + threadIdx.x;
  if (j >= BATCH * S1) return;
  uint32_t col = rand_bits_at(kb0, kb1, (uint32_t)j) & (MAXDEG - 1);
  int b = j / S1;
  hop1[j] = adj[(size_t)node_ids[b] * MAXDEG + col];
}

__global__ void hop2_kernel(const int* __restrict__ hop1,
                            const int* __restrict__ adj,
                            int* __restrict__ hop2,
                            uint32_t kb0, uint32_t kb1) {
  int j = blockIdx.x * blockDim.x + threadIdx.x;
  if (j >= BATCH * S1 * S2) return;
  uint32_t col = rand_bits_at(kb0, kb1, (uint32_t)j) & (MAXDEG - 1);
  hop2[j] = adj[(size_t)hop1[j / S2] * MAXDEG + col];
}

// ---------------- Gather + mean over nrows indexed feature rows ----------------
__global__ __launch_bounds__(64)
void mean_rows_kernel(const float* __restrict__ feat,
                      const int* __restrict__ idx,
                      float* __restrict__ out,
                      int nrows, float inv) {
  const int g = blockIdx.x;
  const int t = threadIdx.x;           // 64 threads x float4 = 256 floats
  const int* rowids = idx + (size_t)g * nrows;
  float4 acc = make_float4(0.f, 0.f, 0.f, 0.f);
  for (int r = 0; r < nrows; ++r) {
    const float4* src = (const float4*)(feat + (size_t)rowids[r] * FDIM);
    float4 v = src[t];
    acc.x += v.x; acc.y += v.y; acc.z += v.z; acc.w += v.w;
  }
  acc.x *= inv; acc.y *= inv; acc.z *= inv; acc.w *= inv;
  ((float4*)(out + (size_t)g * FDIM))[t] = acc;
}

// mean over nrows consecutive rows (h1 -> h1mean)
__global__ __launch_bounds__(64)
void mean_seq_kernel(const float* __restrict__ in, float* __restrict__ out,
                     int nrows, float inv) {
  const int g = blockIdx.x;
  const int t = threadIdx.x;
  const float* base = in + (size_t)g * nrows * FDIM;
  float4 acc = make_float4(0.f, 0.f, 0.f, 0.f);
  for (int r = 0; r < nrows; ++r) {
    float4 v = ((const float4*)(base + (size_t)r * FDIM))[t];
    acc.x += v.x; acc.y += v.y; acc.z += v.z; acc.w += v.w;
  }
  acc.x *= inv; acc.y *= inv; acc.z *= inv; acc.w *= inv;
  ((float4*)(out + (size_t)g * FDIM))[t] = acc;
}

// ---------------- Fused dual GEMM: C[:,0:128]=act(A0@W0), C[:,128:256]=act(A1@W1) ----
// blockIdx.y in {0,1} selects the half. A side is either direct (A ptr, row stride 256)
// or gathered rows of gbase via idx. M must be a multiple of BM. N=128 fixed, K=256.
template<int BM, int TM>
__global__ __launch_bounds__(256)
void gemm2_kernel(const float* __restrict__ A0, const int* __restrict__ idx0,
                  const float* __restrict__ A1, const int* __restrict__ idx1,
                  const float* __restrict__ gbase,
                  const float* __restrict__ W0, const float* __restrict__ W1,
                  float* __restrict__ Cout, int relu) {
  const int half = blockIdx.y;
  const float* A  = half ? A1 : A0;
  const int* idx  = half ? idx1 : idx0;
  const float* W  = half ? W1 : W0;
  const int coff  = half * HDIM;

  const int m0 = blockIdx.x * BM;
  const int tid = threadIdx.x;
  const int tx = tid & 31;        // 32 threads over N (4 cols each -> 128)
  const int ty = tid >> 5;        // 8 threads over M (TM rows each -> BM)

  __shared__ float As[32][BM];    // transposed: As[k][m]
  __shared__ float Bs[32][HDIM];  // Bs[k][n]

  float4 acc[TM];
#pragma unroll
  for (int r = 0; r < TM; ++r) acc[r] = make_float4(0.f, 0.f, 0.f, 0.f);

  for (int kt = 0; kt < FDIM / 32; ++kt) {
    const int k0 = kt * 32;
    // A tile: BM rows x 32 k-cols, stored transposed
    constexpr int NF4 = BM * 8;   // float4 elements in the tile
#pragma unroll
    for (int i = 0; i < (NF4 + 255) / 256; ++i) {
      int f4 = tid + i * 256;
      if (f4 < NF4) {
        int row = f4 >> 3;
        int kc  = (f4 & 7) << 2;
        const float* rp = idx ? (gbase + (size_t)idx[m0 + row] * FDIM)
                              : (A + (size_t)(m0 + row) * FDIM);
        float4 v = *(const float4*)(rp + k0 + kc);
        As[kc + 0][row] = v.x;
        As[kc + 1][row] = v.y;
        As[kc + 2][row] = v.z;
        As[kc + 3][row] = v.w;
      }
    }
    // B tile: 32 x 128
#pragma unroll
    for (int i = 0; i < 4; ++i) {
      int f4 = tid + i * 256;
      int kr = f4 >> 5;
      int c4 = (f4 & 31) << 2;
      *(float4*)&Bs[kr][c4] = *(const float4*)(W + (size_t)(k0 + kr) * HDIM + c4);
    }
    __syncthreads();
#pragma unroll
    for (int kk = 0; kk < 32; ++kk) {
      float a[TM];
#pragma unroll
      for (int r = 0; r < TM; ++r) a[r] = As[kk][ty * TM + r];
      float4 b = *(const float4*)&Bs[kk][tx << 2];
#pragma unroll
      for (int r = 0; r < TM; ++r) {
        acc[r].x += a[r] * b.x; acc[r].y += a[r] * b.y;
        acc[r].z += a[r] * b.z; acc[r].w += a[r] * b.w;
      }
    }
    __syncthreads();
  }
#pragma unroll
  for (int r = 0; r < TM; ++r) {
    int m = m0 + ty * TM + r;
    float4 v = acc[r];
    if (relu) {
      v.x = fmaxf(v.x, 0.f); v.y = fmaxf(v.y, 0.f);
      v.z = fmaxf(v.z, 0.f); v.w = fmaxf(v.w, 0.f);
    }
    *(float4*)(Cout + (size_t)m * (2 * HDIM) + coff + (tx << 2)) = v;
  }
}

// ---------------- l2-normalize + logits + softmax ----------------
__global__ __launch_bounds__(64)
void head_kernel(const float* __restrict__ hmat,
                 const float* __restrict__ Wp,   // [256,41]
                 const float* __restrict__ bp,   // [41]
                 float* __restrict__ out) {
  const int b = blockIdx.x;
  const int t = threadIdx.x;
  __shared__ float hl[2 * HDIM];
  float4 hv = ((const float4*)(hmat + (size_t)b * 2 * HDIM))[t];
  float ss = hv.x * hv.x + hv.y * hv.y + hv.z * hv.z + hv.w * hv.w;
#pragma unroll
  for (int off = 32; off; off >>= 1) ss += __shfl_xor(ss, off, 64);
  float s = rsqrtf(fmaxf(ss, 1e-12f));
  float4 hn = make_float4(hv.x * s, hv.y * s, hv.z * s, hv.w * s);
  ((float4*)hl)[t] = hn;
  __syncthreads();
  float logit = -1e30f;
  if (t < NCLS) {
    logit = bp[t];
    for (int k = 0; k < 2 * HDIM; ++k) logit += hl[k] * Wp[k * NCLS + t];
  }
  float mx = logit;
#pragma unroll
  for (int off = 32; off; off >>= 1) mx = fmaxf(mx, __shfl_xor(mx, off, 64));
  float e = (t < NCLS) ? expf(logit - mx) : 0.f;
  float sum = e;
#pragma unroll
  for (int off = 32; off; off >>= 1) sum += __shfl_xor(sum, off, 64);
  if (t < NCLS) out[(size_t)b * NCLS + t] = e / sum;
}

// ---------------- launch ----------------
extern "C" void kernel_launch(void* const* d_in, const int* in_sizes, int n_in,
                              void* d_out, int out_size, void* d_ws, size_t ws_size,
                              hipStream_t stream) {
  const int*   node_ids = (const int*)d_in[0];
  const float* features = (const float*)d_in[1];
  const int*   adj      = (const int*)d_in[2];
  const float* Ws1      = (const float*)d_in[3];
  const float* Wn1      = (const float*)d_in[4];
  const float* Ws2      = (const float*)d_in[5];
  const float* Wn2      = (const float*)d_in[6];
  const float* Wp       = (const float*)d_in[7];
  const float* bp       = (const float*)d_in[8];
  float* out = (float*)d_out;

  char* ws = (char*)d_ws;
  int*   hop1 = (int*)(ws + 0);              // 25600 i32
  int*   hop2 = (int*)(ws + 102400);         // 256000 i32
  float* n1m  = (float*)(ws + 1126400);      // 1024 x 256
  float* n2m  = (float*)(ws + 2174976);      // 25600 x 256
  float* h1   = (float*)(ws + 28389376);     // 25600 x 256
  float* h1m  = (float*)(ws + 54603776);     // 1024 x 256
  float* h0   = (float*)(ws + 55652352);     // 1024 x 256
  float* hh   = (float*)(ws + 56700928);     // 1024 x 256  (end ~55.1 MB)

  // JAX threefry key chain (partitionable / fold-like split), computed on host:
  // base = key(42) = (0,42); split -> k1=TF(base,(0,0)), k2=TF(base,(0,1));
  // randint internal split -> lower-bits key = TF(k_i,(0,1)).
  uint32_t k1_0, k1_1, k2_0, k2_1, kb1_0, kb1_1, kb2_0, kb2_1;
  tf2x32(0u, 42u, 0u, 0u, k1_0, k1_1);
  tf2x32(0u, 42u, 0u, 1u, k2_0, k2_1);
  tf2x32(k1_0, k1_1, 0u, 1u, kb1_0, kb1_1);
  tf2x32(k2_0, k2_1, 0u, 1u, kb2_0, kb2_1);

  hop1_kernel<<<(BATCH * S1 + 255) / 256, 256, 0, stream>>>(node_ids, adj, hop1, kb1_0, kb1_1);
  hop2_kernel<<<(BATCH * S1 * S2 + 255) / 256, 256, 0, stream>>>(hop1, adj, hop2, kb2_0, kb2_1);

  // neighbor means
  mean_rows_kernel<<<BATCH * S1, 64, 0, stream>>>(features, hop2, n2m, S2, 1.f / S2);
  mean_rows_kernel<<<BATCH, 64, 0, stream>>>(features, hop1, n1m, S1, 1.f / S1);

  // layer 1: h1 = relu([f1@Ws1 ; n2m@Wn1])  (M = 25600)
  dim3 gBig(400, 2);
  gemm2_kernel<64, 8><<<gBig, 256, 0, stream>>>(nullptr, hop1, n2m, nullptr,
                                                features, Ws1, Wn1, h1, 1);
  // layer 1: h0 = relu([f0@Ws1 ; n1m@Wn1])  (M = 1024)
  dim3 gSmall(64, 2);
  gemm2_kernel<16, 2><<<gSmall, 256, 0, stream>>>(nullptr, node_ids, n1m, nullptr,
                                                  features, Ws1, Wn1, h0, 1);
  // mean over S1 of h1
  mean_seq_kernel<<<BATCH, 64, 0, stream>>>(h1, h1m, S1, 1.f / S1);
  // layer 2: h = [h0@Ws2 ; h1m@Wn2]  (no activation)
  gemm2_kernel<16, 2><<<gSmall, 256, 0, stream>>>(h0, nullptr, h1m, nullptr,
                                                  features, Ws2, Wn2, hh, 0);
  // l2norm + logits + softmax
  head_kernel<<<BATCH, 64, 0, stream>>>(hh, Wp, bp, out);
}

// Round 2
// 410.401 us; speedup vs baseline: 1.1286x; 1.1286x over previous
//
#include <hip/hip_runtime.h>
#include <cstdint>
#include <cstddef>

// Problem constants (from reference)
#define BATCH 1024
#define S1 25
#define S2 10
#define FDIM 256
#define HDIM 128
#define NCLS 41
#define MAXDEG 128

typedef __attribute__((ext_vector_type(8))) short bf16x8;
typedef __attribute__((ext_vector_type(4))) float f32x4;

// ---------------- Threefry-2x32 (matches jax partitionable lowering; bit-exact, r1) ---
__host__ __device__ static inline void tf2x32(uint32_t k0, uint32_t k1,
                                              uint32_t c0, uint32_t c1,
                                              uint32_t& o0, uint32_t& o1) {
  const uint32_t ks2 = k0 ^ k1 ^ 0x1BD11BDAu;
  uint32_t x0 = c0 + k0, x1 = c1 + k1;
#define TFR(r) { x0 += x1; x1 = (x1 << (r)) | (x1 >> (32 - (r))); x1 ^= x0; }
  TFR(13) TFR(15) TFR(26) TFR(6)
  x0 += k1;  x1 += ks2 + 1u;
  TFR(17) TFR(29) TFR(16) TFR(24)
  x0 += ks2; x1 += k0 + 2u;
  TFR(13) TFR(15) TFR(26) TFR(6)
  x0 += k0;  x1 += k1 + 3u;
  TFR(17) TFR(29) TFR(16) TFR(24)
  x0 += k1;  x1 += ks2 + 4u;
  TFR(13) TFR(15) TFR(26) TFR(6)
  x0 += ks2; x1 += k0 + 5u;
#undef TFR
  o0 = x0; o1 = x1;
}

__device__ static inline uint32_t rand_bits_at(uint32_t kb0, uint32_t kb1, uint32_t j) {
  uint32_t o0, o1;
  tf2x32(kb0, kb1, 0u, j, o0, o1);
  return o0 ^ o1;
}

// fp32 -> bf16 (RNE)
__device__ static inline ushort f2bf(float x) {
  uint32_t u = __float_as_uint(x);
  return (ushort)((u + 0x7fffu + ((u >> 16) & 1u)) >> 16);
}
__device__ static inline float bf2f(ushort u) {
  uint32_t v = ((uint32_t)u) << 16;
  return __uint_as_float(v);
}

// ---------------- Sampling kernels (bit-exact vs JAX, round-1 verified) -------------
__global__ void hop1_kernel(const int* __restrict__ node_ids,
                            const int* __restrict__ adj,
                            int* __restrict__ hop1,
                            uint32_t kb0, uint32_t kb1) {
  int j = blockIdx.x * blockDim.x + threadIdx.x;
  if (j >= BATCH * S1) return;
  uint32_t col = rand_bits_at(kb0, kb1, (uint32_t)j) & (MAXDEG - 1);
  int b = j / S1;
  hop1[j] = adj[(size_t)node_ids[b] * MAXDEG + col];
}

__global__ void hop2_kernel(const int* __restrict__ hop1,
                            const int* __restrict__ adj,
                            int* __restrict__ hop2,
                            uint32_t kb0, uint32_t kb1) {
  int j = blockIdx.x * blockDim.x + threadIdx.x;
  if (j >= BATCH * S1 * S2) return;
  uint32_t col = rand_bits_at(kb0, kb1, (uint32_t)j) & (MAXDEG - 1);
  hop2[j] = adj[(size_t)hop1[j / S2] * MAXDEG + col];
}

// ---------------- Prep: Ws1/Wn1 -> bf16 transposed [half][n][k] ----------------------
__global__ __launch_bounds__(256)
void prep_w_kernel(const float* __restrict__ Ws1, const float* __restrict__ Wn1,
                   ushort* __restrict__ WbT) {
  // grid 256 blocks: block = (h, n); thread = k
  int h = blockIdx.x >> 7;
  int n = blockIdx.x & 127;
  int k = threadIdx.x;
  const float* W = h ? Wn1 : Ws1;
  WbT[((size_t)(h * HDIM + n)) * FDIM + k] = f2bf(W[(size_t)k * HDIM + n]);
}

// ---------------- meanS2: mean of 10 gathered feature rows -> bf16 ------------------
__global__ __launch_bounds__(256)
void mean2_kernel(const float* __restrict__ feat, const int* __restrict__ hop2,
                  ushort* __restrict__ n2m) {
  int g = blockIdx.x * 4 + (threadIdx.x >> 6);   // (b,s1) group, < 25600
  int t = threadIdx.x & 63;
  const int* rowids = hop2 + (size_t)g * S2;
  float4 acc = make_float4(0.f, 0.f, 0.f, 0.f);
  for (int r = 0; r < S2; ++r) {
    float4 v = ((const float4*)(feat + (size_t)rowids[r] * FDIM))[t];
    acc.x += v.x; acc.y += v.y; acc.z += v.z; acc.w += v.w;
  }
  const float inv = 1.f / S2;
  ushort4 o;
  o.x = f2bf(acc.x * inv); o.y = f2bf(acc.y * inv);
  o.z = f2bf(acc.z * inv); o.w = f2bf(acc.w * inv);
  *(ushort4*)(n2m + (size_t)g * FDIM + t * 4) = o;
}

// ---------------- gather f1 -> bf16 --------------------------------------------------
__global__ __launch_bounds__(256)
void gather_f1_kernel(const float* __restrict__ feat, const int* __restrict__ hop1,
                      ushort* __restrict__ f1b) {
  int g = blockIdx.x * 4 + (threadIdx.x >> 6);   // row < 25600
  int t = threadIdx.x & 63;
  float4 v = ((const float4*)(feat + (size_t)hop1[g] * FDIM))[t];
  ushort4 o;
  o.x = f2bf(v.x); o.y = f2bf(v.y); o.z = f2bf(v.z); o.w = f2bf(v.w);
  *(ushort4*)(f1b + (size_t)g * FDIM + t * 4) = o;
}

// ---------------- meanS1 over f1b rows -> fp32 n1m -----------------------------------
__global__ __launch_bounds__(64)
void mean1_kernel(const ushort* __restrict__ f1b, float* __restrict__ n1m) {
  int b = blockIdx.x;
  int t = threadIdx.x;
  float4 acc = make_float4(0.f, 0.f, 0.f, 0.f);
  for (int r = 0; r < S1; ++r) {
    ushort4 v = *(const ushort4*)(f1b + (size_t)(b * S1 + r) * FDIM + t * 4);
    acc.x += bf2f(v.x); acc.y += bf2f(v.y); acc.z += bf2f(v.z); acc.w += bf2f(v.w);
  }
  const float inv = 1.f / S1;
  acc.x *= inv; acc.y *= inv; acc.z *= inv; acc.w *= inv;
  ((float4*)(n1m + (size_t)b * FDIM))[t] = acc;
}

// ---------------- Big layer-1 GEMM (bf16 MFMA) fused with relu + S1-mean -------------
// grid (400, 2). Block: 256 thr (4 waves), tile 64 rows x 128 cols (one half).
// A = half ? n2m : f1b (bf16, row-major [25600][256]); B = WbT[half] ([128 n][256 k]).
// Epilogue: relu, reduce rows by b-group (b = row/25), atomicAdd into h1m (pre-zeroed).
__global__ __launch_bounds__(256, 2)
void mfma_h1_kernel(const ushort* __restrict__ f1b, const ushort* __restrict__ n2m,
                    const ushort* __restrict__ WbT, float* __restrict__ h1m) {
  const int half = blockIdx.y;
  const ushort* Amat = half ? n2m : f1b;
  const ushort* Bmat = WbT + (size_t)half * HDIM * FDIM;
  const int m0 = blockIdx.x * 64;
  const int tid = threadIdx.x;
  const int wave = tid >> 6;
  const int lane = tid & 63;
  const int lq = lane >> 4;     // quad 0..3
  const int lr = lane & 15;

  __shared__ ushort As[64][40];    // [m][k], +8 pad (80B rows, 16B aligned)
  __shared__ ushort Bs[128][40];   // [n][k], +8 pad
  __shared__ float  Cs[64][132];   // epilogue staging, +4 pad

  f32x4 acc[4][2];
#pragma unroll
  for (int rt = 0; rt < 4; ++rt)
#pragma unroll
    for (int ct = 0; ct < 2; ++ct) acc[rt][ct] = (f32x4)(0.f);

  for (int k0 = 0; k0 < FDIM; k0 += 32) {
    // stage A: 64 rows x 32 k, 16B per thread
    {
      int row = tid >> 2, kc = (tid & 3) * 8;
      int4 v = *(const int4*)(Amat + (size_t)(m0 + row) * FDIM + k0 + kc);
      *(int4*)&As[row][kc] = v;
    }
    // stage B: 128 rows x 32 k, 2 x 16B per thread
#pragma unroll
    for (int i = 0; i < 2; ++i) {
      int idx = tid + i * 256;
      int n = idx >> 2, kc = (idx & 3) * 8;
      int4 v = *(const int4*)(Bmat + (size_t)n * FDIM + k0 + kc);
      *(int4*)&Bs[n][kc] = v;
    }
    __syncthreads();

    bf16x8 af[4];
#pragma unroll
    for (int rt = 0; rt < 4; ++rt)
      af[rt] = *(const bf16x8*)&As[rt * 16 + lr][lq * 8];
#pragma unroll
    for (int ct = 0; ct < 2; ++ct) {
      bf16x8 bf = *(const bf16x8*)&Bs[wave * 32 + ct * 16 + lr][lq * 8];
#pragma unroll
      for (int rt = 0; rt < 4; ++rt)
        acc[rt][ct] = __builtin_amdgcn_mfma_f32_16x16x32_bf16(af[rt], bf, acc[rt][ct], 0, 0, 0);
    }
    __syncthreads();
  }

  // relu -> Cs
#pragma unroll
  for (int rt = 0; rt < 4; ++rt)
#pragma unroll
    for (int ct = 0; ct < 2; ++ct)
#pragma unroll
      for (int r = 0; r < 4; ++r)
        Cs[rt * 16 + lq * 4 + r][wave * 32 + ct * 16 + lr] = fmaxf(acc[rt][ct][r], 0.f);
  __syncthreads();

  // per-b row reduction, one column per thread (128 active)
  if (tid < 128) {
    const int c = tid;
    const int coff = half * HDIM + c;
    float s = 0.f;
    int curb = m0 / S1;
    for (int m = 0; m < 64; ++m) {
      int b = (m0 + m) / S1;             // uniform across threads
      if (b != curb) {
        atomicAdd(&h1m[(size_t)curb * (2 * HDIM) + coff], s * (1.f / S1));
        s = 0.f; curb = b;
      }
      s += Cs[m][c];
    }
    atomicAdd(&h1m[(size_t)curb * (2 * HDIM) + coff], s * (1.f / S1));
  }
}

// ---------------- small fp32 dual GEMM (round-1 verified) ----------------------------
template<int BM, int TM>
__global__ __launch_bounds__(256)
void gemm2_kernel(const float* __restrict__ A0, const int* __restrict__ idx0,
                  const float* __restrict__ A1, const int* __restrict__ idx1,
                  const float* __restrict__ gbase,
                  const float* __restrict__ W0, const float* __restrict__ W1,
                  float* __restrict__ Cout, int relu) {
  const int half = blockIdx.y;
  const float* A  = half ? A1 : A0;
  const int* idx  = half ? idx1 : idx0;
  const float* W  = half ? W1 : W0;
  const int coff  = half * HDIM;

  const int m0 = blockIdx.x * BM;
  const int tid = threadIdx.x;
  const int tx = tid & 31;
  const int ty = tid >> 5;

  __shared__ float As[32][BM];
  __shared__ float Bs[32][HDIM];

  float4 acc[TM];
#pragma unroll
  for (int r = 0; r < TM; ++r) acc[r] = make_float4(0.f, 0.f, 0.f, 0.f);

  for (int kt = 0; kt < FDIM / 32; ++kt) {
    const int k0 = kt * 32;
    constexpr int NF4 = BM * 8;
#pragma unroll
    for (int i = 0; i < (NF4 + 255) / 256; ++i) {
      int f4 = tid + i * 256;
      if (f4 < NF4) {
        int row = f4 >> 3;
        int kc  = (f4 & 7) << 2;
        const float* rp = idx ? (gbase + (size_t)idx[m0 + row] * FDIM)
                              : (A + (size_t)(m0 + row) * FDIM);
        float4 v = *(const float4*)(rp + k0 + kc);
        As[kc + 0][row] = v.x;
        As[kc + 1][row] = v.y;
        As[kc + 2][row] = v.z;
        As[kc + 3][row] = v.w;
      }
    }
#pragma unroll
    for (int i = 0; i < 4; ++i) {
      int f4 = tid + i * 256;
      int kr = f4 >> 5;
      int c4 = (f4 & 31) << 2;
      *(float4*)&Bs[kr][c4] = *(const float4*)(W + (size_t)(k0 + kr) * HDIM + c4);
    }
    __syncthreads();
#pragma unroll
    for (int kk = 0; kk < 32; ++kk) {
      float a[TM];
#pragma unroll
      for (int r = 0; r < TM; ++r) a[r] = As[kk][ty * TM + r];
      float4 b = *(const float4*)&Bs[kk][tx << 2];
#pragma unroll
      for (int r = 0; r < TM; ++r) {
        acc[r].x += a[r] * b.x; acc[r].y += a[r] * b.y;
        acc[r].z += a[r] * b.z; acc[r].w += a[r] * b.w;
      }
    }
    __syncthreads();
  }
#pragma unroll
  for (int r = 0; r < TM; ++r) {
    int m = m0 + ty * TM + r;
    float4 v = acc[r];
    if (relu) {
      v.x = fmaxf(v.x, 0.f); v.y = fmaxf(v.y, 0.f);
      v.z = fmaxf(v.z, 0.f); v.w = fmaxf(v.w, 0.f);
    }
    *(float4*)(Cout + (size_t)m * (2 * HDIM) + coff + (tx << 2)) = v;
  }
}

// ---------------- l2-normalize + logits + softmax (round-1 verified) -----------------
__global__ __launch_bounds__(64)
void head_kernel(const float* __restrict__ hmat,
                 const float* __restrict__ Wp,
                 const float* __restrict__ bp,
                 float* __restrict__ out) {
  const int b = blockIdx.x;
  const int t = threadIdx.x;
  __shared__ float hl[2 * HDIM];
  float4 hv = ((const float4*)(hmat + (size_t)b * 2 * HDIM))[t];
  float ss = hv.x * hv.x + hv.y * hv.y + hv.z * hv.z + hv.w * hv.w;
#pragma unroll
  for (int off = 32; off; off >>= 1) ss += __shfl_xor(ss, off, 64);
  float s = rsqrtf(fmaxf(ss, 1e-12f));
  float4 hn = make_float4(hv.x * s, hv.y * s, hv.z * s, hv.w * s);
  ((float4*)hl)[t] = hn;
  __syncthreads();
  float logit = -1e30f;
  if (t < NCLS) {
    logit = bp[t];
    for (int k = 0; k < 2 * HDIM; ++k) logit += hl[k] * Wp[k * NCLS + t];
  }
  float mx = logit;
#pragma unroll
  for (int off = 32; off; off >>= 1) mx = fmaxf(mx, __shfl_xor(mx, off, 64));
  float e = (t < NCLS) ? expf(logit - mx) : 0.f;
  float sum = e;
#pragma unroll
  for (int off = 32; off; off >>= 1) sum += __shfl_xor(sum, off, 64);
  if (t < NCLS) out[(size_t)b * NCLS + t] = e / sum;
}

// ---------------- launch -------------------------------------------------------------
extern "C" void kernel_launch(void* const* d_in, const int* in_sizes, int n_in,
                              void* d_out, int out_size, void* d_ws, size_t ws_size,
                              hipStream_t stream) {
  const int*   node_ids = (const int*)d_in[0];
  const float* features = (const float*)d_in[1];
  const int*   adj      = (const int*)d_in[2];
  const float* Ws1      = (const float*)d_in[3];
  const float* Wn1      = (const float*)d_in[4];
  const float* Ws2      = (const float*)d_in[5];
  const float* Wn2      = (const float*)d_in[6];
  const float* Wp       = (const float*)d_in[7];
  const float* bp       = (const float*)d_in[8];
  float* out = (float*)d_out;

  char* ws = (char*)d_ws;
  int*    hop1 = (int*)(ws + 0);              // 25600 i32
  int*    hop2 = (int*)(ws + 102400);         // 256000 i32
  ushort* f1b  = (ushort*)(ws + 1126400);     // 25600 x 256 bf16
  ushort* n2m  = (ushort*)(ws + 14233600);    // 25600 x 256 bf16
  ushort* WbT  = (ushort*)(ws + 27340800);    // 2 x 128 x 256 bf16
  float*  n1m  = (float*)(ws + 27471872);     // 1024 x 256 f32
  float*  h1m  = (float*)(ws + 28520448);     // 1024 x 256 f32
  float*  h0   = (float*)(ws + 29569024);     // 1024 x 256 f32
  float*  hh   = (float*)(ws + 30617600);     // 1024 x 256 f32

  // JAX threefry key chain (bit-exact, round-1 verified)
  uint32_t k1_0, k1_1, k2_0, k2_1, kb1_0, kb1_1, kb2_0, kb2_1;
  tf2x32(0u, 42u, 0u, 0u, k1_0, k1_1);
  tf2x32(0u, 42u, 0u, 1u, k2_0, k2_1);
  tf2x32(k1_0, k1_1, 0u, 1u, kb1_0, kb1_1);
  tf2x32(k2_0, k2_1, 0u, 1u, kb2_0, kb2_1);

  hop1_kernel<<<(BATCH * S1 + 255) / 256, 256, 0, stream>>>(node_ids, adj, hop1, kb1_0, kb1_1);
  hop2_kernel<<<(BATCH * S1 * S2 + 255) / 256, 256, 0, stream>>>(hop1, adj, hop2, kb2_0, kb2_1);

  prep_w_kernel<<<256, 256, 0, stream>>>(Ws1, Wn1, WbT);
  hipMemsetAsync(h1m, 0, (size_t)BATCH * 2 * HDIM * sizeof(float), stream);

  gather_f1_kernel<<<BATCH * S1 / 4, 256, 0, stream>>>(features, hop1, f1b);
  mean2_kernel<<<BATCH * S1 / 4, 256, 0, stream>>>(features, hop2, n2m);
  mean1_kernel<<<BATCH, 64, 0, stream>>>(f1b, n1m);

  // fused big GEMM + relu + S1-mean -> h1m
  dim3 gBig(BATCH * S1 / 64, 2);
  mfma_h1_kernel<<<gBig, 256, 0, stream>>>(f1b, n2m, WbT, h1m);

  // layer 1 (self batch): h0 = relu([f0@Ws1 ; n1m@Wn1])  (fp32)
  dim3 gSmall(BATCH / 16, 2);
  gemm2_kernel<16, 2><<<gSmall, 256, 0, stream>>>(nullptr, node_ids, n1m, nullptr,
                                                  features, Ws1, Wn1, h0, 1);
  // layer 2: hh = [h0@Ws2 ; h1m@Wn2]  (fp32)
  gemm2_kernel<16, 2><<<gSmall, 256, 0, stream>>>(h0, nullptr, h1m, nullptr,
                                                  features, Ws2, Wn2, hh, 0);
  head_kernel<<<BATCH, 64, 0, stream>>>(hh, Wp, bp, out);
}

// Round 3
// 386.260 us; speedup vs baseline: 1.1992x; 1.0625x over previous
//
#include <hip/hip_runtime.h>
#include <cstdint>
#include <cstddef>

// Problem constants (from reference)
#define BATCH 1024
#define S1 25
#define S2 10
#define FDIM 256
#define HDIM 128
#define NCLS 41
#define MAXDEG 128

typedef __attribute__((ext_vector_type(8))) short bf16x8;
typedef __attribute__((ext_vector_type(4))) float f32x4;

// ---------------- Threefry-2x32 (bit-exact vs JAX partitionable; r1-verified) --------
__host__ __device__ static inline void tf2x32(uint32_t k0, uint32_t k1,
                                              uint32_t c0, uint32_t c1,
                                              uint32_t& o0, uint32_t& o1) {
  const uint32_t ks2 = k0 ^ k1 ^ 0x1BD11BDAu;
  uint32_t x0 = c0 + k0, x1 = c1 + k1;
#define TFR(r) { x0 += x1; x1 = (x1 << (r)) | (x1 >> (32 - (r))); x1 ^= x0; }
  TFR(13) TFR(15) TFR(26) TFR(6)
  x0 += k1;  x1 += ks2 + 1u;
  TFR(17) TFR(29) TFR(16) TFR(24)
  x0 += ks2; x1 += k0 + 2u;
  TFR(13) TFR(15) TFR(26) TFR(6)
  x0 += k0;  x1 += k1 + 3u;
  TFR(17) TFR(29) TFR(16) TFR(24)
  x0 += k1;  x1 += ks2 + 4u;
  TFR(13) TFR(15) TFR(26) TFR(6)
  x0 += ks2; x1 += k0 + 5u;
#undef TFR
  o0 = x0; o1 = x1;
}

__device__ static inline uint32_t rand_bits_at(uint32_t kb0, uint32_t kb1, uint32_t j) {
  uint32_t o0, o1;
  tf2x32(kb0, kb1, 0u, j, o0, o1);
  return o0 ^ o1;
}

// fp32 -> bf16 (RNE) — identical to r2 (values bit-preserved)
__device__ static inline ushort f2bf(float x) {
  uint32_t u = __float_as_uint(x);
  return (ushort)((u + 0x7fffu + ((u >> 16) & 1u)) >> 16);
}

// ================= K1: fused sampling + n2m + n1m + Wprep + h1m-zero =================
// blocks [0,6400): 4 waves x (sample hop1/hop2 inline, mean-of-10 feature rows -> bf16 n2m)
// blocks [6400,6656): 4 waves x (per-b mean-of-25 hop1 feature rows -> fp32 n1m)
// blocks [6656,6912): Ws1/Wn1 -> bf16 transposed WbT[h*128+n][k]
// blocks [6912,7168): zero h1m (1 MB)
__global__ __launch_bounds__(256)
void prep_kernel(const int* __restrict__ node_ids, const float* __restrict__ feat,
                 const int* __restrict__ adj,
                 const float* __restrict__ Ws1, const float* __restrict__ Wn1,
                 int* __restrict__ hop1g, ushort* __restrict__ n2m,
                 float* __restrict__ n1m, ushort* __restrict__ WbT,
                 float* __restrict__ h1m,
                 uint32_t kb1_0, uint32_t kb1_1, uint32_t kb2_0, uint32_t kb2_1) {
  const int blk = blockIdx.x;
  const int t = threadIdx.x;
  if (blk < 6400) {
    const int wave = t >> 6, lane = t & 63;
    const int g = blk * 4 + wave;          // 0..25599
    const int b = g / S1;
    int hop1v = 0;
    if (lane == 0) {
      uint32_t c1 = rand_bits_at(kb1_0, kb1_1, (uint32_t)g) & (MAXDEG - 1);
      hop1v = adj[(size_t)node_ids[b] * MAXDEG + c1];
    }
    hop1v = __shfl(hop1v, 0, 64);
    if (lane == 0) hop1g[g] = hop1v;
    int r2id = 0;
    if (lane < S2) {
      uint32_t c2 = rand_bits_at(kb2_0, kb2_1, (uint32_t)(g * S2 + lane)) & (MAXDEG - 1);
      r2id = adj[(size_t)hop1v * MAXDEG + c2];
    }
    float4 acc = make_float4(0.f, 0.f, 0.f, 0.f);
#pragma unroll
    for (int r = 0; r < S2; ++r) {
      int rid = __shfl(r2id, r, 64);
      float4 v = ((const float4*)(feat + (size_t)rid * FDIM))[lane];
      acc.x += v.x; acc.y += v.y; acc.z += v.z; acc.w += v.w;
    }
    const float inv = 1.f / S2;
    ushort4 o;
    o.x = f2bf(acc.x * inv); o.y = f2bf(acc.y * inv);
    o.z = f2bf(acc.z * inv); o.w = f2bf(acc.w * inv);
    *(ushort4*)(n2m + (size_t)g * FDIM + lane * 4) = o;
  } else if (blk < 6656) {
    const int wave = t >> 6, lane = t & 63;
    const int b = (blk - 6400) * 4 + wave; // 0..1023
    int h1v = 0;
    if (lane < S1) {
      uint32_t c1 = rand_bits_at(kb1_0, kb1_1, (uint32_t)(b * S1 + lane)) & (MAXDEG - 1);
      h1v = adj[(size_t)node_ids[b] * MAXDEG + c1];
    }
    float4 acc = make_float4(0.f, 0.f, 0.f, 0.f);
#pragma unroll
    for (int r = 0; r < S1; ++r) {
      int rid = __shfl(h1v, r, 64);
      float4 v = ((const float4*)(feat + (size_t)rid * FDIM))[lane];
      acc.x += v.x; acc.y += v.y; acc.z += v.z; acc.w += v.w;
    }
    const float inv = 1.f / S1;
    acc.x *= inv; acc.y *= inv; acc.z *= inv; acc.w *= inv;
    ((float4*)(n1m + (size_t)b * FDIM))[lane] = acc;
  } else if (blk < 6912) {
    const int idx = blk - 6656;            // h*128+n
    const int h = idx >> 7, n = idx & 127;
    const float* W = h ? Wn1 : Ws1;
    WbT[(size_t)idx * FDIM + t] = f2bf(W[(size_t)t * HDIM + n]);
  } else {
    const int i = (blk - 6912) * 256 + t;  // 65536 float4 = 1 MB
    ((float4*)h1m)[i] = make_float4(0.f, 0.f, 0.f, 0.f);
  }
}

// ================= K2: bf16 MFMA layer-1 GEMM + relu + S1-mean (r2-verified core) ====
// grid (400, 2). half 0: A rows gathered fp32->bf16 from features[hop1[m]];
// half 1: A rows = n2m (bf16). B = WbT[half]. Epilogue: relu + per-b mean via atomics.
__global__ __launch_bounds__(256, 2)
void mfma_h1_kernel(const int* __restrict__ hop1g, const float* __restrict__ feat,
                    const ushort* __restrict__ n2m, const ushort* __restrict__ WbT,
                    float* __restrict__ h1m) {
  const int half = blockIdx.y;
  const ushort* Bmat = WbT + (size_t)half * HDIM * FDIM;
  const int m0 = blockIdx.x * 64;
  const int tid = threadIdx.x;
  const int wave = tid >> 6;
  const int lane = tid & 63;
  const int lq = lane >> 4;
  const int lr = lane & 15;

  __shared__ ushort As[64][40];
  __shared__ ushort Bs[128][40];
  __shared__ float  Cs[64][132];
  __shared__ int rowid[64];

  if (half == 0 && tid < 64) rowid[tid] = hop1g[m0 + tid];
  __syncthreads();

  f32x4 acc[4][2];
#pragma unroll
  for (int rt = 0; rt < 4; ++rt)
#pragma unroll
    for (int ct = 0; ct < 2; ++ct) acc[rt][ct] = (f32x4)(0.f);

  for (int k0 = 0; k0 < FDIM; k0 += 32) {
    const int row = tid >> 2, kc = (tid & 3) * 8;
    if (half == 0) {
      const float* rp = feat + (size_t)rowid[row] * FDIM + k0 + kc;
      float4 v0 = *(const float4*)rp;
      float4 v1 = *(const float4*)(rp + 4);
      union { ushort u[8]; int4 v; } pk;
      pk.u[0] = f2bf(v0.x); pk.u[1] = f2bf(v0.y); pk.u[2] = f2bf(v0.z); pk.u[3] = f2bf(v0.w);
      pk.u[4] = f2bf(v1.x); pk.u[5] = f2bf(v1.y); pk.u[6] = f2bf(v1.z); pk.u[7] = f2bf(v1.w);
      *(int4*)&As[row][kc] = pk.v;
    } else {
      int4 v = *(const int4*)(n2m + (size_t)(m0 + row) * FDIM + k0 + kc);
      *(int4*)&As[row][kc] = v;
    }
#pragma unroll
    for (int i = 0; i < 2; ++i) {
      int idx = tid + i * 256;
      int n = idx >> 2, kc2 = (idx & 3) * 8;
      int4 v = *(const int4*)(Bmat + (size_t)n * FDIM + k0 + kc2);
      *(int4*)&Bs[n][kc2] = v;
    }
    __syncthreads();

    bf16x8 af[4];
#pragma unroll
    for (int rt = 0; rt < 4; ++rt)
      af[rt] = *(const bf16x8*)&As[rt * 16 + lr][lq * 8];
#pragma unroll
    for (int ct = 0; ct < 2; ++ct) {
      bf16x8 bf = *(const bf16x8*)&Bs[wave * 32 + ct * 16 + lr][lq * 8];
#pragma unroll
      for (int rt = 0; rt < 4; ++rt)
        acc[rt][ct] = __builtin_amdgcn_mfma_f32_16x16x32_bf16(af[rt], bf, acc[rt][ct], 0, 0, 0);
    }
    __syncthreads();
  }

#pragma unroll
  for (int rt = 0; rt < 4; ++rt)
#pragma unroll
    for (int ct = 0; ct < 2; ++ct)
#pragma unroll
      for (int r = 0; r < 4; ++r)
        Cs[rt * 16 + lq * 4 + r][wave * 32 + ct * 16 + lr] = fmaxf(acc[rt][ct][r], 0.f);
  __syncthreads();

  if (tid < 128) {
    const int c = tid;
    const int coff = half * HDIM + c;
    float s = 0.f;
    int curb = m0 / S1;
    for (int m = 0; m < 64; ++m) {
      int b = (m0 + m) / S1;
      if (b != curb) {
        atomicAdd(&h1m[(size_t)curb * (2 * HDIM) + coff], s * (1.f / S1));
        s = 0.f; curb = b;
      }
      s += Cs[m][c];
    }
    atomicAdd(&h1m[(size_t)curb * (2 * HDIM) + coff], s * (1.f / S1));
  }
}

// ================= K3: fused layer1-self + layer2 + l2norm + logits + softmax ========
// 256 blocks x 256 thr; block handles 4 batch rows. All fp32, intermediates in LDS.
__global__ __launch_bounds__(256)
void tail_kernel(const int* __restrict__ node_ids, const float* __restrict__ feat,
                 const float* __restrict__ n1m, const float* __restrict__ h1m,
                 const float* __restrict__ Ws1, const float* __restrict__ Wn1,
                 const float* __restrict__ Ws2, const float* __restrict__ Wn2,
                 const float* __restrict__ Wp, const float* __restrict__ bp,
                 float* __restrict__ out) {
  const int b0 = blockIdx.x * 4;
  const int t = threadIdx.x;
  const int wave = t >> 6, lane = t & 63;

  __shared__ float A0[4][256];   // f0 rows
  __shared__ float A1[4][256];   // n1m rows
  __shared__ float H1[4][256];   // h1m rows
  __shared__ float H0[4][256];   // relu(layer1-self)
  __shared__ float HN[4][256];   // l2-normalized hh
  __shared__ float red[4][4];    // [wave][r]
  __shared__ float scl[4];
  __shared__ float lg[4][NCLS];
  __shared__ float sm[4][2];

  {
    const int r = wave;
    const int nid = node_ids[b0 + r];
    ((float4*)A0[r])[lane] = ((const float4*)(feat + (size_t)nid * FDIM))[lane];
    ((float4*)A1[r])[lane] = ((const float4*)(n1m + (size_t)(b0 + r) * FDIM))[lane];
    ((float4*)H1[r])[lane] = ((const float4*)(h1m + (size_t)(b0 + r) * FDIM))[lane];
  }
  __syncthreads();

  const int h = t >> 7, c = t & 127;
  // phase 1: h0 = relu([f0@Ws1 ; n1m@Wn1]), column t
  {
    const float* W = h ? Wn1 : Ws1;
    const float* Ap = h ? &A1[0][0] : &A0[0][0];
    float acc[4] = {0.f, 0.f, 0.f, 0.f};
    for (int k4 = 0; k4 < 64; ++k4) {
      float w0 = W[(size_t)(k4 * 4 + 0) * HDIM + c];
      float w1 = W[(size_t)(k4 * 4 + 1) * HDIM + c];
      float w2 = W[(size_t)(k4 * 4 + 2) * HDIM + c];
      float w3 = W[(size_t)(k4 * 4 + 3) * HDIM + c];
#pragma unroll
      for (int r = 0; r < 4; ++r) {
        float4 a = ((const float4*)(Ap + r * 256))[k4];
        acc[r] += a.x * w0 + a.y * w1 + a.z * w2 + a.w * w3;
      }
    }
#pragma unroll
    for (int r = 0; r < 4; ++r) H0[r][t] = fmaxf(acc[r], 0.f);
  }
  __syncthreads();

  // phase 2: hh = [H0@Ws2 ; H1@Wn2] (no act), column t
  float hv[4];
  {
    const float* W = h ? Wn2 : Ws2;
    const float* Ap = h ? &H1[0][0] : &H0[0][0];
    float acc[4] = {0.f, 0.f, 0.f, 0.f};
    for (int k4 = 0; k4 < 64; ++k4) {
      float w0 = W[(size_t)(k4 * 4 + 0) * HDIM + c];
      float w1 = W[(size_t)(k4 * 4 + 1) * HDIM + c];
      float w2 = W[(size_t)(k4 * 4 + 2) * HDIM + c];
      float w3 = W[(size_t)(k4 * 4 + 3) * HDIM + c];
#pragma unroll
      for (int r = 0; r < 4; ++r) {
        float4 a = ((const float4*)(Ap + r * 256))[k4];
        acc[r] += a.x * w0 + a.y * w1 + a.z * w2 + a.w * w3;
      }
    }
#pragma unroll
    for (int r = 0; r < 4; ++r) hv[r] = acc[r];
  }

  // phase 3: l2 normalize per row
  {
    float ss[4];
#pragma unroll
    for (int r = 0; r < 4; ++r) ss[r] = hv[r] * hv[r];
#pragma unroll
    for (int off = 32; off; off >>= 1)
#pragma unroll
      for (int r = 0; r < 4; ++r) ss[r] += __shfl_xor(ss[r], off, 64);
    if (lane == 0) {
#pragma unroll
      for (int r = 0; r < 4; ++r) red[wave][r] = ss[r];
    }
  }
  __syncthreads();
  if (t < 4) {
    float tot = red[0][t] + red[1][t] + red[2][t] + red[3][t];
    scl[t] = rsqrtf(fmaxf(tot, 1e-12f));
  }
  __syncthreads();
#pragma unroll
  for (int r = 0; r < 4; ++r) HN[r][t] = hv[r] * scl[r];
  __syncthreads();

  // phase 4: logits + softmax
  int rr = 0, cc = 0;
  float logit = 0.f;
  if (t < 4 * NCLS) {
    rr = t / NCLS; cc = t - rr * NCLS;
    float acc = bp[cc];
    for (int k = 0; k < 2 * HDIM; ++k) acc += HN[rr][k] * Wp[(size_t)k * NCLS + cc];
    lg[rr][cc] = acc;
    logit = acc;
  }
  __syncthreads();
  if (t < 4) {
    float m = -1e30f;
    for (int i = 0; i < NCLS; ++i) m = fmaxf(m, lg[t][i]);
    float s = 0.f;
    for (int i = 0; i < NCLS; ++i) s += expf(lg[t][i] - m);
    sm[t][0] = m; sm[t][1] = s;
  }
  __syncthreads();
  if (t < 4 * NCLS)
    out[(size_t)(b0 + rr) * NCLS + cc] = expf(logit - sm[rr][0]) / sm[rr][1];
}

// ================= launch ============================================================
extern "C" void kernel_launch(void* const* d_in, const int* in_sizes, int n_in,
                              void* d_out, int out_size, void* d_ws, size_t ws_size,
                              hipStream_t stream) {
  const int*   node_ids = (const int*)d_in[0];
  const float* features = (const float*)d_in[1];
  const int*   adj      = (const int*)d_in[2];
  const float* Ws1      = (const float*)d_in[3];
  const float* Wn1      = (const float*)d_in[4];
  const float* Ws2      = (const float*)d_in[5];
  const float* Wn2      = (const float*)d_in[6];
  const float* Wp       = (const float*)d_in[7];
  const float* bp       = (const float*)d_in[8];
  float* out = (float*)d_out;

  char* ws = (char*)d_ws;
  int*    hop1 = (int*)(ws + 0);              // 25600 i32        (100 KB)
  ushort* n2m  = (ushort*)(ws + 102400);      // 25600x256 bf16   (12.5 MB)
  ushort* WbT  = (ushort*)(ws + 13209600);    // 2x128x256 bf16   (128 KB)
  float*  n1m  = (float*)(ws + 13340672);     // 1024x256 f32     (1 MB)
  float*  h1m  = (float*)(ws + 14389248);     // 1024x256 f32     (1 MB)

  // JAX threefry key chain (bit-exact, r1-verified)
  uint32_t k1_0, k1_1, k2_0, k2_1, kb1_0, kb1_1, kb2_0, kb2_1;
  tf2x32(0u, 42u, 0u, 0u, k1_0, k1_1);
  tf2x32(0u, 42u, 0u, 1u, k2_0, k2_1);
  tf2x32(k1_0, k1_1, 0u, 1u, kb1_0, kb1_1);
  tf2x32(k2_0, k2_1, 0u, 1u, kb2_0, kb2_1);

  prep_kernel<<<7168, 256, 0, stream>>>(node_ids, features, adj, Ws1, Wn1,
                                        hop1, n2m, n1m, WbT, h1m,
                                        kb1_0, kb1_1, kb2_0, kb2_1);

  dim3 gBig(BATCH * S1 / 64, 2);
  mfma_h1_kernel<<<gBig, 256, 0, stream>>>(hop1, features, n2m, WbT, h1m);

  tail_kernel<<<BATCH / 4, 256, 0, stream>>>(node_ids, features, n1m, h1m,
                                             Ws1, Wn1, Ws2, Wn2, Wp, bp, out);
}